// Round 13
// baseline (277.460 us; speedup 1.0000x reference)
//
#include <hip/hip_runtime.h>

typedef __attribute__((ext_vector_type(4))) float floatx4;
typedef __attribute__((ext_vector_type(8))) __bf16 bf16x8;
typedef __attribute__((ext_vector_type(8))) unsigned short ushort8;
typedef __attribute__((ext_vector_type(4))) unsigned short ushort4v;

#define MFMA16(a, b, c) __builtin_amdgcn_mfma_f32_16x16x32_bf16((a), (b), (c), 0, 0, 0)

static __device__ __forceinline__ unsigned short f2bu(float f) {
  unsigned int u = __builtin_bit_cast(unsigned int, f);
  unsigned int r = (u + 0x7fffu + ((u >> 16) & 1u)) >> 16;
  return (unsigned short)r;
}

static __device__ __forceinline__ unsigned int cvtpk(float lo, float hi) {
  unsigned int r;
  asm("v_cvt_pk_bf16_f32 %0, %1, %2" : "=v"(r) : "v"(lo), "v"(hi));
  return r;
}

static __device__ __forceinline__ float fexp2(float x) {
  float r;
  asm("v_exp_f32 %0, %1" : "=v"(r) : "v"(x));
  return r;
}

static __device__ __forceinline__ void gload_lds16(const void* g, void* l) {
  __builtin_amdgcn_global_load_lds((const __attribute__((address_space(1))) void*)g,
                                   (__attribute__((address_space(3))) void*)l, 16, 0, 0);
}

// ---------------- fused f32 -> bf16 cast for all 5 inputs ----------------
__global__ void cast_all(const float* __restrict__ x,  unsigned short* __restrict__ xb,
                         const float* __restrict__ w0, unsigned short* __restrict__ w0b,
                         const float* __restrict__ w1, unsigned short* __restrict__ w1b,
                         const float* __restrict__ w2, unsigned short* __restrict__ w2b,
                         const float* __restrict__ w3, unsigned short* __restrict__ w3b) {
  int i = blockIdx.x * blockDim.x + threadIdx.x;  // over float4s; 3145728 total
  const float* src;
  unsigned short* dst;
  int j;
  if (i < 2097152) {
    src = x; dst = xb; j = i;
  } else {
    j = i - 2097152;
    int wsel = j >> 18;          // 262144 float4 per weight
    j &= 262143;
    src = (wsel == 0) ? w0 : (wsel == 1) ? w1 : (wsel == 2) ? w2 : w3;
    dst = (wsel == 0) ? w0b : (wsel == 1) ? w1b : (wsel == 2) ? w2b : w3b;
  }
  float4 v = reinterpret_cast<const float4*>(src)[j];
  ushort4v o;
  o.x = f2bu(v.x); o.y = f2bu(v.y); o.z = f2bu(v.z); o.w = f2bu(v.w);
  reinterpret_cast<ushort4v*>(dst)[j] = o;
}

// ---------------- shared GEMM core: C[128x128] = A[128xK] * W[128 rows of K]^T ----------------
// Double-buffered 2-phase prefetch (round-7 version; no LDS swizzle).
static __device__ __forceinline__ void gemm_core(const unsigned short* __restrict__ Ag,
                                                 const unsigned short* __restrict__ Wg,
                                                 int tm0, int tn0,
                                                 unsigned short* As, unsigned short* Bs,
                                                 floatx4 acc[4][4]) {
  const int tid = threadIdx.x;
  const int w = tid >> 6, l = tid & 63;
  const int lg = l >> 4, lq = l & 15;
  const int wr = w >> 1, wc = w & 1;

  const int srow = w * 32 + (l >> 2);
  const int scol = (l & 3) * 8;
  const unsigned short* ga = Ag + (size_t)(tm0 + srow) * 1024 + scol;
  const unsigned short* gb = Wg + (size_t)(tn0 + srow) * 1024 + scol;
  const int ldst0 = w * 1024;          // elements; wave writes rows w*32..w*32+15
  const int ldst1 = ldst0 + 16 * 32;   // rows w*32+16..31

#define GSTAGE(bi, kt_)                                   \
  do {                                                    \
    const int ko_ = (kt_) * 32;                           \
    gload_lds16(ga + ko_,              As + (bi) * 4096 + ldst0); \
    gload_lds16(ga + ko_ + 16 * 1024,  As + (bi) * 4096 + ldst1); \
    gload_lds16(gb + ko_,              Bs + (bi) * 4096 + ldst0); \
    gload_lds16(gb + ko_ + 16 * 1024,  Bs + (bi) * 4096 + ldst1); \
  } while (0)

  GSTAGE(0, 0);
  __syncthreads();
  int buf = 0;
  for (int kt = 0; kt < 32; ++kt) {
    if (kt + 1 < 32) GSTAGE(buf ^ 1, kt + 1);
    bf16x8 ar[4], br[4];
#pragma unroll
    for (int i = 0; i < 4; ++i) {
      ar[i] = *(const bf16x8*)(As + buf * 4096 + (wr * 64 + i * 16 + lq) * 32 + lg * 8);
      br[i] = *(const bf16x8*)(Bs + buf * 4096 + (wc * 64 + i * 16 + lq) * 32 + lg * 8);
    }
#pragma unroll
    for (int i = 0; i < 4; ++i)
#pragma unroll
      for (int j = 0; j < 4; ++j)
        acc[i][j] = MFMA16(ar[i], br[j], acc[i][j]);
    __syncthreads();   // drains own vmcnt(0) (next-tile stage) + cross-wave barrier
    buf ^= 1;
  }
#undef GSTAGE
}

// ---------------- QKV projection GEMM ----------------
// z=0: Q (scaled 1/8 * log2e) -> Qb [BH][T][D];  z=1: K -> Kb [BH][T][D];  z=2: V -> Vtb [BH][D][T]
__global__ __launch_bounds__(256, 4) void gemm_qkv(const unsigned short* __restrict__ xb,
                                                   const unsigned short* __restrict__ Wqb,
                                                   const unsigned short* __restrict__ Wkb,
                                                   const unsigned short* __restrict__ Wvb,
                                                   unsigned short* __restrict__ Qb,
                                                   unsigned short* __restrict__ Kb,
                                                   unsigned short* __restrict__ Vtb) {
  __shared__ unsigned short As[2 * 128 * 32];
  __shared__ unsigned short Bs[2 * 128 * 32];
  const int tid = threadIdx.x;
  const int w = tid >> 6, l = tid & 63;
  const int lg = l >> 4, lq = l & 15;
  const int wr = w >> 1, wc = w & 1;
  const int tm0 = blockIdx.x * 128;
  const int tn0 = blockIdx.y * 128;
  const int z = blockIdx.z;
  const unsigned short* W = (z == 0) ? Wqb : (z == 1) ? Wkb : Wvb;

  floatx4 acc[4][4];
#pragma unroll
  for (int i = 0; i < 4; ++i)
#pragma unroll
    for (int j = 0; j < 4; ++j) acc[i][j] = (floatx4){0.f, 0.f, 0.f, 0.f};

  gemm_core(xb, W, tm0, tn0, As, Bs, acc);

  const int b = tm0 >> 11;
  const int t0 = tm0 & 2047;

  if (z == 2) {
#pragma unroll
    for (int mi = 0; mi < 4; ++mi)
#pragma unroll
      for (int ni = 0; ni < 4; ++ni) {
        int t = t0 + wr * 64 + mi * 16 + lg * 4;
        int n = tn0 + wc * 64 + ni * 16 + lq;
        int h = n >> 6, d = n & 63;
        ushort4v o;
        o.x = f2bu(acc[mi][ni][0]);
        o.y = f2bu(acc[mi][ni][1]);
        o.z = f2bu(acc[mi][ni][2]);
        o.w = f2bu(acc[mi][ni][3]);
        *(ushort4v*)(Vtb + ((size_t)(b * 16 + h) * 64 + d) * 2048 + t) = o;
      }
  } else {
    // Q: fold softmax scale 1/sqrt(64) AND log2(e) so attention can use exp2
    float sc = (z == 0) ? 0.125f * 1.44269504f : 1.0f;
    unsigned short* dst = (z == 0) ? Qb : Kb;
#pragma unroll
    for (int mi = 0; mi < 4; ++mi)
#pragma unroll
      for (int ni = 0; ni < 4; ++ni) {
        int n = tn0 + wc * 64 + ni * 16 + lq;
        int h = n >> 6, d = n & 63;
#pragma unroll
        for (int r = 0; r < 4; ++r) {
          int t = t0 + wr * 64 + mi * 16 + lg * 4 + r;
          dst[((size_t)(b * 16 + h) * 2048 + t) * 64 + d] = f2bu(acc[mi][ni][r] * sc);
        }
      }
  }
}

// ---------------- flash attention (causal), LDS-staged, double-buffered ----------------
// Dispatch-order-independent load balance: block = 2 waves (128 thr), wave owns
// 64 q-rows (qh=4), block q-tile = 128 rows; block SEQUENTIALLY processes
// qt = pr then 15-pr  ->  every block exactly 34 k-tile steps, no assumption
// about block->CU assignment. Grid (64,8) = 512 blocks = 2/CU; co-resident
// block covers drain stalls. K/Vt XOR-swizzled LDS via pre-swizzled
// global_load_lds source (8 issues/wave/step). 32 KiB LDS.
// Row-sum via ones-MFMA; defer-max rescale (THR=11, log2 domain).
__global__ __launch_bounds__(128, 2) void attn_fwd(const unsigned short* __restrict__ Qb,
                                                   const unsigned short* __restrict__ Kb,
                                                   const unsigned short* __restrict__ Vtb,
                                                   unsigned short* __restrict__ attb) {
  constexpr int T = 2048;
  __shared__ char Ls[32768];
  const int bh = blockIdx.x;
  const int pr = blockIdx.y;           // 0..7
  const int tid = threadIdx.x;
  const int w = tid >> 6, l = tid & 63;
  const int lg = l >> 4, lq = l & 15;

  const char* Kgc = (const char*)(Kb + (size_t)bh * T * 64);
  const char* Vgc = (const char*)(Vtb + (size_t)bh * 64 * T);
  const unsigned short* Qp = Qb + (size_t)bh * T * 64;

  // staging: per issue, wave covers 8 rows x 128B; 4 K issues + 4 V issues per wave.
  const int scolx = ((l & 7) << 4) ^ ((l >> 3) << 4);      // pre-swizzled source col
  const int koff0 = (w * 32 + (l >> 3)) * 128 + scolx;     // K rows: 128B stride
  const int voff0 = (w * 32 + (l >> 3)) * 4096 + scolx;    // Vt rows: 4096B stride
  char* Ks = (char*)Ls;
  char* Vs = (char*)Ls + 16384;
  const int kswz = (lq & 7) << 4;
  const int ldw = w * 4096;            // wave's dest half within 8KB buffer
  const int b = bh >> 4, h = bh & 15;

  const ushort8 onesu = {0x3F80, 0x3F80, 0x3F80, 0x3F80, 0x3F80, 0x3F80, 0x3F80, 0x3F80};
  const bf16x8 onesf = __builtin_bit_cast(bf16x8, onesu);

#define STAGE(bi, kb_)                                               \
  do {                                                               \
    const char* kg_ = Kgc + (size_t)(kb_) * 128 + koff0;             \
    const char* vg_ = Vgc + (size_t)(kb_) * 2 + voff0;               \
    _Pragma("unroll")                                                \
    for (int i_ = 0; i_ < 4; ++i_) {                                 \
      gload_lds16(kg_ + i_ * 1024,  Ks + (bi) * 8192 + ldw + i_ * 1024); \
      gload_lds16(vg_ + i_ * 32768, Vs + (bi) * 8192 + ldw + i_ * 1024); \
    }                                                                \
  } while (0)

  for (int pi = 0; pi < 2; ++pi) {
    const int qt = pi ? (15 - pr) : pr;    // pair sums to 34 steps for every block
    const int q0 = qt * 128 + w * 64;      // wave's first q row (64 rows)

    bf16x8 qf[4][2];
#pragma unroll
    for (int qh = 0; qh < 4; ++qh) {
      qf[qh][0] = *(const bf16x8*)(Qp + (size_t)(q0 + qh * 16 + lq) * 64 + lg * 8);
      qf[qh][1] = *(const bf16x8*)(Qp + (size_t)(q0 + qh * 16 + lq) * 64 + 32 + lg * 8);
    }

    floatx4 acc[4][4];
#pragma unroll
    for (int qh = 0; qh < 4; ++qh)
#pragma unroll
      for (int dc = 0; dc < 4; ++dc) acc[qh][dc] = (floatx4){0.f, 0.f, 0.f, 0.f};
    floatx4 rsum[4];
#pragma unroll
    for (int qh = 0; qh < 4; ++qh) rsum[qh] = (floatx4){0.f, 0.f, 0.f, 0.f};
    float m_run[4] = {-1e30f, -1e30f, -1e30f, -1e30f};

    const int nt = 2 * qt + 2;
    int buf = 0;
    STAGE(0, 0);
    __syncthreads();

    for (int t = 0; t < nt; ++t) {
      if (t + 1 < nt) STAGE(buf ^ 1, (t + 1) * 64);
      const int kb = t * 64;
      if (kb <= q0 + 63) {  // wave-uniform: skip tiles fully above this wave's rows
        const char* Kl = Ks + buf * 8192;
        const char* Vl = Vs + buf * 8192;

        // --- S^T = K * Q^T : s[qh][kc][r] = S[q=q0+qh*16+lq][k = kb+kc*16+lg*4+r]
        floatx4 s[4][4];
#pragma unroll
        for (int kc = 0; kc < 4; ++kc) {
          const int rowb = (kc * 16 + lq) * 128;
          bf16x8 kf0 = *(const bf16x8*)(Kl + rowb + ((lg * 16) ^ kswz));
          bf16x8 kf1 = *(const bf16x8*)(Kl + rowb + ((64 + lg * 16) ^ kswz));
#pragma unroll
          for (int qh = 0; qh < 4; ++qh) {
            floatx4 tt = (floatx4){0.f, 0.f, 0.f, 0.f};
            tt = MFMA16(kf0, qf[qh][0], tt);
            tt = MFMA16(kf1, qf[qh][1], tt);
            s[qh][kc] = tt;
          }
        }

        if (kb + 63 > q0) {  // diagonal region for this wave: causal mask
#pragma unroll
          for (int qh = 0; qh < 4; ++qh) {
            const int qrow = q0 + qh * 16 + lq;
#pragma unroll
            for (int kc = 0; kc < 4; ++kc)
#pragma unroll
              for (int r = 0; r < 4; ++r)
                if (kb + kc * 16 + lg * 4 + r > qrow) s[qh][kc][r] = -1e30f;
          }
        }

        // --- online softmax per q-fragment (base-2 domain; defer-max THR=11)
        bf16x8 pa[4][2];
#pragma unroll
        for (int qh = 0; qh < 4; ++qh) {
          float m0 = fmaxf(fmaxf(s[qh][0][0], s[qh][0][1]), fmaxf(s[qh][0][2], s[qh][0][3]));
          float m1 = fmaxf(fmaxf(s[qh][1][0], s[qh][1][1]), fmaxf(s[qh][1][2], s[qh][1][3]));
          float m2 = fmaxf(fmaxf(s[qh][2][0], s[qh][2][1]), fmaxf(s[qh][2][2], s[qh][2][3]));
          float m3 = fmaxf(fmaxf(s[qh][3][0], s[qh][3][1]), fmaxf(s[qh][3][2], s[qh][3][3]));
          float mt = fmaxf(fmaxf(m0, m1), fmaxf(m2, m3));
          mt = fmaxf(mt, __shfl_xor(mt, 16, 64));
          mt = fmaxf(mt, __shfl_xor(mt, 32, 64));
          if (__any(mt > m_run[qh] + 11.f)) {
            float mn = fmaxf(m_run[qh], mt);
            float corr = fexp2(m_run[qh] - mn);
#pragma unroll
            for (int dc = 0; dc < 4; ++dc) acc[qh][dc] *= corr;
            rsum[qh] *= corr;
            m_run[qh] = mn;
          }
          float p[4][4];
#pragma unroll
          for (int kc = 0; kc < 4; ++kc)
#pragma unroll
            for (int r = 0; r < 4; ++r) p[kc][r] = fexp2(s[qh][kc][r] - m_run[qh]);

          int4 u0, u1;
          u0.x = cvtpk(p[0][0], p[0][1]); u0.y = cvtpk(p[0][2], p[0][3]);
          u0.z = cvtpk(p[1][0], p[1][1]); u0.w = cvtpk(p[1][2], p[1][3]);
          u1.x = cvtpk(p[2][0], p[2][1]); u1.y = cvtpk(p[2][2], p[2][3]);
          u1.z = cvtpk(p[3][0], p[3][1]); u1.w = cvtpk(p[3][2], p[3][3]);
          pa[qh][0] = __builtin_bit_cast(bf16x8, u0);
          pa[qh][1] = __builtin_bit_cast(bf16x8, u1);

          rsum[qh] = MFMA16(onesf, pa[qh][0], rsum[qh]);
          rsum[qh] = MFMA16(onesf, pa[qh][1], rsum[qh]);
        }

        // --- out^T += V^T * P^T : V fragment read once, feeds all 4 q-fragments
#pragma unroll
        for (int dc = 0; dc < 4; ++dc) {
          const int rowb = (dc * 16 + lq) * 128;
#pragma unroll
          for (int kk = 0; kk < 2; ++kk) {
            ushort4v v0 = *(const ushort4v*)(Vl + rowb + ((kk * 64 + lg * 8) ^ kswz));
            ushort4v v1 = *(const ushort4v*)(Vl + rowb + ((kk * 64 + lg * 8 + 32) ^ kswz));
            ushort8 vv = __builtin_shufflevector(v0, v1, 0, 1, 2, 3, 4, 5, 6, 7);
            bf16x8 va = __builtin_bit_cast(bf16x8, vv);
#pragma unroll
            for (int qh = 0; qh < 4; ++qh)
              acc[qh][dc] = MFMA16(va, pa[qh][kk], acc[qh][dc]);
          }
        }
      }
      __syncthreads();
      buf ^= 1;
    }

    // --- finalize + store: att[b*T + q][h*64 + d]
#pragma unroll
    for (int qh = 0; qh < 4; ++qh) {
      float inv = 1.f / rsum[qh][0];
      unsigned short* orow = attb + (size_t)(b * 2048 + q0 + qh * 16 + lq) * 1024 + h * 64;
#pragma unroll
      for (int dc = 0; dc < 4; ++dc) {
        ushort4v o;
        o.x = f2bu(acc[qh][dc][0] * inv);
        o.y = f2bu(acc[qh][dc][1] * inv);
        o.z = f2bu(acc[qh][dc][2] * inv);
        o.w = f2bu(acc[qh][dc][3] * inv);
        *(ushort4v*)(orow + 16 * dc + lg * 4) = o;
      }
    }
  }
#undef STAGE
}

// ---------------- output projection: out = att @ Wo^T + bo (f32 out) ----------------
__global__ __launch_bounds__(256, 4) void gemm_out(const unsigned short* __restrict__ attb,
                                                   const unsigned short* __restrict__ Wob,
                                                   const float* __restrict__ bo,
                                                   float* __restrict__ out) {
  __shared__ unsigned short As[2 * 128 * 32];
  __shared__ unsigned short Bs[2 * 128 * 32];
  const int tid = threadIdx.x;
  const int w = tid >> 6, l = tid & 63;
  const int lg = l >> 4, lq = l & 15;
  const int wr = w >> 1, wc = w & 1;
  const int tm0 = blockIdx.x * 128;
  const int tn0 = blockIdx.y * 128;

  floatx4 acc[4][4];
#pragma unroll
  for (int i = 0; i < 4; ++i)
#pragma unroll
    for (int j = 0; j < 4; ++j) acc[i][j] = (floatx4){0.f, 0.f, 0.f, 0.f};

  gemm_core(attb, Wob, tm0, tn0, As, Bs, acc);

#pragma unroll
  for (int mi = 0; mi < 4; ++mi)
#pragma unroll
    for (int ni = 0; ni < 4; ++ni) {
      int row = tm0 + wr * 64 + mi * 16 + lg * 4;
      int col = tn0 + wc * 64 + ni * 16 + lq;
      float bias = bo[col];
#pragma unroll
      for (int r = 0; r < 4; ++r)
        out[(size_t)(row + r) * 1024 + col] = acc[mi][ni][r] + bias;
    }
}

extern "C" void kernel_launch(void* const* d_in, const int* in_sizes, int n_in,
                              void* d_out, int out_size, void* d_ws, size_t ws_size,
                              hipStream_t stream) {
  const float* x  = (const float*)d_in[0];
  const float* Wq = (const float*)d_in[1];
  const float* Wk = (const float*)d_in[2];
  const float* Wv = (const float*)d_in[3];
  const float* Wo = (const float*)d_in[4];
  const float* bo = (const float*)d_in[5];
  float* out = (float*)d_out;

  unsigned short* ws = (unsigned short*)d_ws;
  unsigned short* xb  = ws;                    // 8388608
  unsigned short* Wqb = ws + 8388608;          // 1048576
  unsigned short* Wkb = ws + 9437184;
  unsigned short* Wvb = ws + 10485760;
  unsigned short* Wob = ws + 11534336;
  unsigned short* Qb  = ws + 12582912;         // [BH][T][D]
  unsigned short* Kb  = ws + 20971520;         // [BH][T][D]
  unsigned short* Vtb = ws + 29360128;         // [BH][D][T]
  unsigned short* attb= ws + 37748736;         // [B*T][C]

  cast_all<<<12288, 256, 0, stream>>>(x, xb, Wq, Wqb, Wk, Wkb, Wv, Wvb, Wo, Wob);

  gemm_qkv<<<dim3(64, 8, 3), 256, 0, stream>>>(xb, Wqb, Wkb, Wvb, Qb, Kb, Vtb);
  attn_fwd<<<dim3(64, 8), 128, 0, stream>>>(Qb, Kb, Vtb, attb);
  gemm_out<<<dim3(64, 8), 256, 0, stream>>>(attb, Wob, bo, out);
}

// Round 15
// 249.525 us; speedup vs baseline: 1.1120x; 1.1120x over previous
//
#include <hip/hip_runtime.h>

typedef __attribute__((ext_vector_type(4))) float floatx4;
typedef __attribute__((ext_vector_type(8))) __bf16 bf16x8;
typedef __attribute__((ext_vector_type(8))) unsigned short ushort8;
typedef __attribute__((ext_vector_type(4))) unsigned short ushort4v;

#define MFMA16(a, b, c) __builtin_amdgcn_mfma_f32_16x16x32_bf16((a), (b), (c), 0, 0, 0)

static __device__ __forceinline__ unsigned short f2bu(float f) {
  unsigned int u = __builtin_bit_cast(unsigned int, f);
  unsigned int r = (u + 0x7fffu + ((u >> 16) & 1u)) >> 16;
  return (unsigned short)r;
}

static __device__ __forceinline__ unsigned int cvtpk(float lo, float hi) {
  unsigned int r;
  asm("v_cvt_pk_bf16_f32 %0, %1, %2" : "=v"(r) : "v"(lo), "v"(hi));
  return r;
}

static __device__ __forceinline__ float fexp2(float x) {
  float r;
  asm("v_exp_f32 %0, %1" : "=v"(r) : "v"(x));
  return r;
}

static __device__ __forceinline__ void gload_lds16(const void* g, void* l) {
  __builtin_amdgcn_global_load_lds((const __attribute__((address_space(1))) void*)g,
                                   (__attribute__((address_space(3))) void*)l, 16, 0, 0);
}

// ---------------- fused f32 -> bf16 cast for all 5 inputs ----------------
__global__ void cast_all(const float* __restrict__ x,  unsigned short* __restrict__ xb,
                         const float* __restrict__ w0, unsigned short* __restrict__ w0b,
                         const float* __restrict__ w1, unsigned short* __restrict__ w1b,
                         const float* __restrict__ w2, unsigned short* __restrict__ w2b,
                         const float* __restrict__ w3, unsigned short* __restrict__ w3b) {
  int i = blockIdx.x * blockDim.x + threadIdx.x;  // over float4s; 3145728 total
  const float* src;
  unsigned short* dst;
  int j;
  if (i < 2097152) {
    src = x; dst = xb; j = i;
  } else {
    j = i - 2097152;
    int wsel = j >> 18;          // 262144 float4 per weight
    j &= 262143;
    src = (wsel == 0) ? w0 : (wsel == 1) ? w1 : (wsel == 2) ? w2 : w3;
    dst = (wsel == 0) ? w0b : (wsel == 1) ? w1b : (wsel == 2) ? w2b : w3b;
  }
  float4 v = reinterpret_cast<const float4*>(src)[j];
  ushort4v o;
  o.x = f2bu(v.x); o.y = f2bu(v.y); o.z = f2bu(v.z); o.w = f2bu(v.w);
  reinterpret_cast<ushort4v*>(dst)[j] = o;
}

// ---------------- shared GEMM core: C[128x128] = A[128xK] * W[128 rows of K]^T ----------------
// Double-buffered 2-phase prefetch (round-7 version; no LDS swizzle).
static __device__ __forceinline__ void gemm_core(const unsigned short* __restrict__ Ag,
                                                 const unsigned short* __restrict__ Wg,
                                                 int tm0, int tn0,
                                                 unsigned short* As, unsigned short* Bs,
                                                 floatx4 acc[4][4]) {
  const int tid = threadIdx.x;
  const int w = tid >> 6, l = tid & 63;
  const int lg = l >> 4, lq = l & 15;
  const int wr = w >> 1, wc = w & 1;

  const int srow = w * 32 + (l >> 2);
  const int scol = (l & 3) * 8;
  const unsigned short* ga = Ag + (size_t)(tm0 + srow) * 1024 + scol;
  const unsigned short* gb = Wg + (size_t)(tn0 + srow) * 1024 + scol;
  const int ldst0 = w * 1024;          // elements; wave writes rows w*32..w*32+15
  const int ldst1 = ldst0 + 16 * 32;   // rows w*32+16..31

#define GSTAGE(bi, kt_)                                   \
  do {                                                    \
    const int ko_ = (kt_) * 32;                           \
    gload_lds16(ga + ko_,              As + (bi) * 4096 + ldst0); \
    gload_lds16(ga + ko_ + 16 * 1024,  As + (bi) * 4096 + ldst1); \
    gload_lds16(gb + ko_,              Bs + (bi) * 4096 + ldst0); \
    gload_lds16(gb + ko_ + 16 * 1024,  Bs + (bi) * 4096 + ldst1); \
  } while (0)

  GSTAGE(0, 0);
  __syncthreads();
  int buf = 0;
  for (int kt = 0; kt < 32; ++kt) {
    if (kt + 1 < 32) GSTAGE(buf ^ 1, kt + 1);
    bf16x8 ar[4], br[4];
#pragma unroll
    for (int i = 0; i < 4; ++i) {
      ar[i] = *(const bf16x8*)(As + buf * 4096 + (wr * 64 + i * 16 + lq) * 32 + lg * 8);
      br[i] = *(const bf16x8*)(Bs + buf * 4096 + (wc * 64 + i * 16 + lq) * 32 + lg * 8);
    }
#pragma unroll
    for (int i = 0; i < 4; ++i)
#pragma unroll
      for (int j = 0; j < 4; ++j)
        acc[i][j] = MFMA16(ar[i], br[j], acc[i][j]);
    __syncthreads();   // drains own vmcnt(0) (next-tile stage) + cross-wave barrier
    buf ^= 1;
  }
#undef GSTAGE
}

// ---------------- QKV projection GEMM ----------------
// z=0: Q (scaled 1/8 * log2e) -> Qb [BH][T][D];  z=1: K -> Kb [BH][T][D];  z=2: V -> Vtb [BH][D][T]
__global__ __launch_bounds__(256, 4) void gemm_qkv(const unsigned short* __restrict__ xb,
                                                   const unsigned short* __restrict__ Wqb,
                                                   const unsigned short* __restrict__ Wkb,
                                                   const unsigned short* __restrict__ Wvb,
                                                   unsigned short* __restrict__ Qb,
                                                   unsigned short* __restrict__ Kb,
                                                   unsigned short* __restrict__ Vtb) {
  __shared__ unsigned short As[2 * 128 * 32];
  __shared__ unsigned short Bs[2 * 128 * 32];
  const int tid = threadIdx.x;
  const int w = tid >> 6, l = tid & 63;
  const int lg = l >> 4, lq = l & 15;
  const int wr = w >> 1, wc = w & 1;
  const int tm0 = blockIdx.x * 128;
  const int tn0 = blockIdx.y * 128;
  const int z = blockIdx.z;
  const unsigned short* W = (z == 0) ? Wqb : (z == 1) ? Wkb : Wvb;

  floatx4 acc[4][4];
#pragma unroll
  for (int i = 0; i < 4; ++i)
#pragma unroll
    for (int j = 0; j < 4; ++j) acc[i][j] = (floatx4){0.f, 0.f, 0.f, 0.f};

  gemm_core(xb, W, tm0, tn0, As, Bs, acc);

  const int b = tm0 >> 11;
  const int t0 = tm0 & 2047;

  if (z == 2) {
#pragma unroll
    for (int mi = 0; mi < 4; ++mi)
#pragma unroll
      for (int ni = 0; ni < 4; ++ni) {
        int t = t0 + wr * 64 + mi * 16 + lg * 4;
        int n = tn0 + wc * 64 + ni * 16 + lq;
        int h = n >> 6, d = n & 63;
        ushort4v o;
        o.x = f2bu(acc[mi][ni][0]);
        o.y = f2bu(acc[mi][ni][1]);
        o.z = f2bu(acc[mi][ni][2]);
        o.w = f2bu(acc[mi][ni][3]);
        *(ushort4v*)(Vtb + ((size_t)(b * 16 + h) * 64 + d) * 2048 + t) = o;
      }
  } else {
    // Q: fold softmax scale 1/sqrt(64) AND log2(e) so attention can use exp2
    float sc = (z == 0) ? 0.125f * 1.44269504f : 1.0f;
    unsigned short* dst = (z == 0) ? Qb : Kb;
#pragma unroll
    for (int mi = 0; mi < 4; ++mi)
#pragma unroll
      for (int ni = 0; ni < 4; ++ni) {
        int n = tn0 + wc * 64 + ni * 16 + lq;
        int h = n >> 6, d = n & 63;
#pragma unroll
        for (int r = 0; r < 4; ++r) {
          int t = t0 + wr * 64 + mi * 16 + lg * 4 + r;
          dst[((size_t)(b * 16 + h) * 2048 + t) * 64 + d] = f2bu(acc[mi][ni][r] * sc);
        }
      }
  }
}

// ---------------- flash attention (causal), LDS-staged, double-buffered ----------------
// Round-11 structure (validated: 4 waves x 64 q-rows (qh=4), 256-row tile/block,
// grid (64,8)=512 blocks, 8 waves/CU) with PAIR-SUM-CONSTANT qt map:
// co-resident blocks are (k, k+256) = (pr, pr+4); map pr->qt = [7,5,6,4,0,2,1,3]
// gives qt(pr)+qt(pr+4)=7 for every pair -> each CU's block pair costs exactly
// 36 steps (was 16..56 with round-11's interleave map; critical path 56).
// K/Vt XOR-swizzled LDS via pre-swizzled global_load_lds source. 32 KiB LDS.
// Row-sum via ones-MFMA; defer-max rescale (THR=11, log2 domain).
__global__ __launch_bounds__(256, 2) void attn_fwd(const unsigned short* __restrict__ Qb,
                                                   const unsigned short* __restrict__ Kb,
                                                   const unsigned short* __restrict__ Vtb,
                                                   unsigned short* __restrict__ attb) {
  constexpr int T = 2048;
  __shared__ char Ls[32768];
  const int bh = blockIdx.x;
  const int qt = (0x31204657u >> (blockIdx.y * 4)) & 7;  // pr: 0->7,1->5,2->6,3->4,4->0,5->2,6->1,7->3
  const int tid = threadIdx.x;
  const int w = tid >> 6, l = tid & 63;
  const int lg = l >> 4, lq = l & 15;

  const char* Kgc = (const char*)(Kb + (size_t)bh * T * 64);
  const char* Vgc = (const char*)(Vtb + (size_t)bh * 64 * T);
  const unsigned short* Qp = Qb + (size_t)bh * T * 64;

  const int scolx = ((tid & 7) << 4) ^ (((tid >> 3) & 7) << 4);
  const int koff = ((tid >> 3) << 7) + scolx;    // K rows: 128B stride
  const int voff = ((tid >> 3) << 12) + scolx;   // Vt rows: 4096B stride
  char* Ks = (char*)Ls;
  char* Vs = (char*)Ls + 16384;
  const int kswz = (lq & 7) << 4;
  const int wofs = w * 1024;
  const int b = bh >> 4, h = bh & 15;

  const ushort8 onesu = {0x3F80, 0x3F80, 0x3F80, 0x3F80, 0x3F80, 0x3F80, 0x3F80, 0x3F80};
  const bf16x8 onesf = __builtin_bit_cast(bf16x8, onesu);

#define STAGE(bi, kb_)                                               \
  do {                                                               \
    const char* kg_ = Kgc + (size_t)(kb_) * 128 + koff;              \
    const char* vg_ = Vgc + (size_t)(kb_) * 2 + voff;                \
    gload_lds16(kg_,          Ks + (bi) * 8192 + wofs);              \
    gload_lds16(kg_ + 4096,   Ks + (bi) * 8192 + 4096 + wofs);       \
    gload_lds16(vg_,          Vs + (bi) * 8192 + wofs);              \
    gload_lds16(vg_ + 131072, Vs + (bi) * 8192 + 4096 + wofs);       \
  } while (0)

  const int q0 = qt * 256 + w * 64;   // wave's first q row (64 rows: qh=0..3, +lq)

  bf16x8 qf[4][2];
#pragma unroll
  for (int qh = 0; qh < 4; ++qh) {
    qf[qh][0] = *(const bf16x8*)(Qp + (size_t)(q0 + qh * 16 + lq) * 64 + lg * 8);
    qf[qh][1] = *(const bf16x8*)(Qp + (size_t)(q0 + qh * 16 + lq) * 64 + 32 + lg * 8);
  }

  floatx4 acc[4][4];
#pragma unroll
  for (int qh = 0; qh < 4; ++qh)
#pragma unroll
    for (int dc = 0; dc < 4; ++dc) acc[qh][dc] = (floatx4){0.f, 0.f, 0.f, 0.f};
  floatx4 rsum[4];
#pragma unroll
  for (int qh = 0; qh < 4; ++qh) rsum[qh] = (floatx4){0.f, 0.f, 0.f, 0.f};
  float m_run[4] = {-1e30f, -1e30f, -1e30f, -1e30f};

  const int nt = 4 * qt + 4;
  int buf = 0;
  STAGE(0, 0);
  __syncthreads();

  for (int t = 0; t < nt; ++t) {
    if (t + 1 < nt) STAGE(buf ^ 1, (t + 1) * 64);
    const int kb = t * 64;
    if (kb <= q0 + 63) {  // wave-uniform: skip tiles fully above this wave's rows
      const char* Kl = Ks + buf * 8192;
      const char* Vl = Vs + buf * 8192;

      // --- S^T = K * Q^T : s[qh][kc][r] = S[q=q0+qh*16+lq][k = kb+kc*16+lg*4+r]
      floatx4 s[4][4];
#pragma unroll
      for (int kc = 0; kc < 4; ++kc) {
        const int rowb = (kc * 16 + lq) * 128;
        bf16x8 kf0 = *(const bf16x8*)(Kl + rowb + ((lg * 16) ^ kswz));
        bf16x8 kf1 = *(const bf16x8*)(Kl + rowb + ((64 + lg * 16) ^ kswz));
#pragma unroll
        for (int qh = 0; qh < 4; ++qh) {
          floatx4 tt = (floatx4){0.f, 0.f, 0.f, 0.f};
          tt = MFMA16(kf0, qf[qh][0], tt);
          tt = MFMA16(kf1, qf[qh][1], tt);
          s[qh][kc] = tt;
        }
      }

      if (kb + 63 > q0) {  // diagonal region for this wave: causal mask
#pragma unroll
        for (int qh = 0; qh < 4; ++qh) {
          const int qrow = q0 + qh * 16 + lq;
#pragma unroll
          for (int kc = 0; kc < 4; ++kc)
#pragma unroll
            for (int r = 0; r < 4; ++r)
              if (kb + kc * 16 + lg * 4 + r > qrow) s[qh][kc][r] = -1e30f;
        }
      }

      // --- online softmax per q-fragment (base-2 domain; defer-max THR=11)
      bf16x8 pa[4][2];
#pragma unroll
      for (int qh = 0; qh < 4; ++qh) {
        float m0 = fmaxf(fmaxf(s[qh][0][0], s[qh][0][1]), fmaxf(s[qh][0][2], s[qh][0][3]));
        float m1 = fmaxf(fmaxf(s[qh][1][0], s[qh][1][1]), fmaxf(s[qh][1][2], s[qh][1][3]));
        float m2 = fmaxf(fmaxf(s[qh][2][0], s[qh][2][1]), fmaxf(s[qh][2][2], s[qh][2][3]));
        float m3 = fmaxf(fmaxf(s[qh][3][0], s[qh][3][1]), fmaxf(s[qh][3][2], s[qh][3][3]));
        float mt = fmaxf(fmaxf(m0, m1), fmaxf(m2, m3));
        mt = fmaxf(mt, __shfl_xor(mt, 16, 64));
        mt = fmaxf(mt, __shfl_xor(mt, 32, 64));
        if (__any(mt > m_run[qh] + 11.f)) {
          float mn = fmaxf(m_run[qh], mt);
          float corr = fexp2(m_run[qh] - mn);
#pragma unroll
          for (int dc = 0; dc < 4; ++dc) acc[qh][dc] *= corr;
          rsum[qh] *= corr;
          m_run[qh] = mn;
        }
        float p[4][4];
#pragma unroll
        for (int kc = 0; kc < 4; ++kc)
#pragma unroll
          for (int r = 0; r < 4; ++r) p[kc][r] = fexp2(s[qh][kc][r] - m_run[qh]);

        int4 u0, u1;
        u0.x = cvtpk(p[0][0], p[0][1]); u0.y = cvtpk(p[0][2], p[0][3]);
        u0.z = cvtpk(p[1][0], p[1][1]); u0.w = cvtpk(p[1][2], p[1][3]);
        u1.x = cvtpk(p[2][0], p[2][1]); u1.y = cvtpk(p[2][2], p[2][3]);
        u1.z = cvtpk(p[3][0], p[3][1]); u1.w = cvtpk(p[3][2], p[3][3]);
        pa[qh][0] = __builtin_bit_cast(bf16x8, u0);
        pa[qh][1] = __builtin_bit_cast(bf16x8, u1);

        rsum[qh] = MFMA16(onesf, pa[qh][0], rsum[qh]);
        rsum[qh] = MFMA16(onesf, pa[qh][1], rsum[qh]);
      }

      // --- out^T += V^T * P^T : V fragment read once, feeds all 4 q-fragments
#pragma unroll
      for (int dc = 0; dc < 4; ++dc) {
        const int rowb = (dc * 16 + lq) * 128;
#pragma unroll
        for (int kk = 0; kk < 2; ++kk) {
          ushort4v v0 = *(const ushort4v*)(Vl + rowb + ((kk * 64 + lg * 8) ^ kswz));
          ushort4v v1 = *(const ushort4v*)(Vl + rowb + ((kk * 64 + lg * 8 + 32) ^ kswz));
          ushort8 vv = __builtin_shufflevector(v0, v1, 0, 1, 2, 3, 4, 5, 6, 7);
          bf16x8 va = __builtin_bit_cast(bf16x8, vv);
#pragma unroll
          for (int qh = 0; qh < 4; ++qh)
            acc[qh][dc] = MFMA16(va, pa[qh][kk], acc[qh][dc]);
        }
      }
    }
    __syncthreads();
    buf ^= 1;
  }

  // --- finalize + store: att[b*T + q][h*64 + d]
#pragma unroll
  for (int qh = 0; qh < 4; ++qh) {
    float inv = 1.f / rsum[qh][0];
    unsigned short* orow = attb + (size_t)(b * 2048 + q0 + qh * 16 + lq) * 1024 + h * 64;
#pragma unroll
    for (int dc = 0; dc < 4; ++dc) {
      ushort4v o;
      o.x = f2bu(acc[qh][dc][0] * inv);
      o.y = f2bu(acc[qh][dc][1] * inv);
      o.z = f2bu(acc[qh][dc][2] * inv);
      o.w = f2bu(acc[qh][dc][3] * inv);
      *(ushort4v*)(orow + 16 * dc + lg * 4) = o;
    }
  }
#undef STAGE
}

// ---------------- output projection: out = att @ Wo^T + bo (f32 out) ----------------
__global__ __launch_bounds__(256, 4) void gemm_out(const unsigned short* __restrict__ attb,
                                                   const unsigned short* __restrict__ Wob,
                                                   const float* __restrict__ bo,
                                                   float* __restrict__ out) {
  __shared__ unsigned short As[2 * 128 * 32];
  __shared__ unsigned short Bs[2 * 128 * 32];
  const int tid = threadIdx.x;
  const int w = tid >> 6, l = tid & 63;
  const int lg = l >> 4, lq = l & 15;
  const int wr = w >> 1, wc = w & 1;
  const int tm0 = blockIdx.x * 128;
  const int tn0 = blockIdx.y * 128;

  floatx4 acc[4][4];
#pragma unroll
  for (int i = 0; i < 4; ++i)
#pragma unroll
    for (int j = 0; j < 4; ++j) acc[i][j] = (floatx4){0.f, 0.f, 0.f, 0.f};

  gemm_core(attb, Wob, tm0, tn0, As, Bs, acc);

#pragma unroll
  for (int mi = 0; mi < 4; ++mi)
#pragma unroll
    for (int ni = 0; ni < 4; ++ni) {
      int row = tm0 + wr * 64 + mi * 16 + lg * 4;
      int col = tn0 + wc * 64 + ni * 16 + lq;
      float bias = bo[col];
#pragma unroll
      for (int r = 0; r < 4; ++r)
        out[(size_t)(row + r) * 1024 + col] = acc[mi][ni][r] + bias;
    }
}

extern "C" void kernel_launch(void* const* d_in, const int* in_sizes, int n_in,
                              void* d_out, int out_size, void* d_ws, size_t ws_size,
                              hipStream_t stream) {
  const float* x  = (const float*)d_in[0];
  const float* Wq = (const float*)d_in[1];
  const float* Wk = (const float*)d_in[2];
  const float* Wv = (const float*)d_in[3];
  const float* Wo = (const float*)d_in[4];
  const float* bo = (const float*)d_in[5];
  float* out = (float*)d_out;

  unsigned short* ws = (unsigned short*)d_ws;
  unsigned short* xb  = ws;                    // 8388608
  unsigned short* Wqb = ws + 8388608;          // 1048576
  unsigned short* Wkb = ws + 9437184;
  unsigned short* Wvb = ws + 10485760;
  unsigned short* Wob = ws + 11534336;
  unsigned short* Qb  = ws + 12582912;         // [BH][T][D]
  unsigned short* Kb  = ws + 20971520;         // [BH][T][D]
  unsigned short* Vtb = ws + 29360128;         // [BH][D][T]
  unsigned short* attb= ws + 37748736;         // [B*T][C]

  cast_all<<<12288, 256, 0, stream>>>(x, xb, Wq, Wqb, Wk, Wkb, Wv, Wvb, Wo, Wob);

  gemm_qkv<<<dim3(64, 8, 3), 256, 0, stream>>>(xb, Wqb, Wkb, Wvb, Qb, Kb, Vtb);
  attn_fwd<<<dim3(64, 8), 256, 0, stream>>>(Qb, Kb, Vtb, attb);
  gemm_out<<<dim3(64, 8), 256, 0, stream>>>(attb, Wob, bo, out);
}